// Round 1
// baseline (148.046 us; speedup 1.0000x reference)
//
#include <hip/hip_runtime.h>

#define B 2
#define W 4096
#define R 8
#define D 32
#define L 64
#define C (W / L)   // 64 chunks

// ---------------------------------------------------------------------------
// Kernel 1: per-chunk local decayed state
//   S_loc[b,c,r,d] = sum_{j=0..L-1} gamma_r^(L-1-j) * k[b,cL+j,r] * h[b,cL+j,d]
// 512 threads: even/odd-j split halves the serial decay chain (32 deep, g^2 step).
// ---------------------------------------------------------------------------
__global__ __launch_bounds__(512) void k_local(const float* __restrict__ kin,
                                               const float* __restrict__ hin,
                                               const float* __restrict__ gamma_vec,
                                               float* __restrict__ ws_state) {
    __shared__ float sk[L][R];        // 2 KB
    __shared__ float sh[L][D];        // 8 KB
    __shared__ float part[2][R][D];   // 2 KB
    const int blk = blockIdx.x;
    const int b = blk / C, c = blk % C;
    const int t = threadIdx.x;
    const float* kp = kin + ((size_t)b * W + (size_t)c * L) * R;   // [L][R]
    const float* hp = hin + ((size_t)b * W + (size_t)c * L) * D;   // [L][D]
    ((float*)sk)[t] = kp[t];                       // 512 floats
    ((float4*)sh)[t] = ((const float4*)hp)[t];     // 2048 floats
    __syncthreads();
    const int half = t >> 8;          // 0: even j, 1: odd j
    const int rd = t & 255;
    const int r = rd >> 5, d = rd & 31;
    const float g = gamma_vec[r];
    const float g2 = g * g;
    float S = 0.f;
    // ascending m with multiplier g^2: S_half = sum_m (g^2)^(31-m) * kh[2m+half]
#pragma unroll
    for (int m = 0; m < 32; ++m) {
        const int j = 2 * m + half;
        S = S * g2 + sk[j][r] * sh[j][d];
    }
    part[half][r][d] = S;
    __syncthreads();
    if (t < 256) {
        // g^(63-j): odd j -> (g^2)^((63-j)/2) = part[1]; even j -> g*(g^2)^((62-j)/2)
        ws_state[(size_t)(b * C + c) * R * D + rd] = part[1][r][d] + g * part[0][r][d];
    }
}

// ---------------------------------------------------------------------------
// Kernel 2 (fused scan + output):
//   P_c[r,d]   = sum_{c'<c} (gamma_r^L)^(c-1-c') * S_loc[c']          (per-block redux)
//   out[b,i,d] = sum_r q[i,r]*gamma_r^(i+1)*P_c[r,d]
//              + sum_{j<=i} A[i][j]*h[j,d],  A[i][j]=sum_r q[i,r]k[j,r]gamma_r^(i-j)
// A stored transposed+padded: conflict-free writes, broadcast b128 reads.
// ---------------------------------------------------------------------------
__global__ __launch_bounds__(512) void k_out(const float* __restrict__ qin,
                                             const float* __restrict__ kin,
                                             const float* __restrict__ hin,
                                             const float* __restrict__ gamma_vec,
                                             const float* __restrict__ ws_state,
                                             float* __restrict__ out) {
    __shared__ float sq[L][R + 1];                      // pad 9: conflict-free lane-i reads
    __shared__ float sk[L][R];
    __shared__ float sh[L][D];
    __shared__ __align__(16) float sAT[L][L + 4];       // A^T [j][i], pad 68 (17 KB)
    __shared__ float spow[R][L + 1];                    // gamma_r^delta
    __shared__ float s0[R][D];                          // carried-in state P_c
    const int blk = blockIdx.x;
    const int b = blk / C, c = blk % C;
    const int t = threadIdx.x;
    const size_t row0 = (size_t)b * W + (size_t)c * L;
    const float* qp = qin + row0 * R;
    const float* kp = kin + row0 * R;
    const float* hp = hin + row0 * D;
    sq[t >> 3][t & 7] = qp[t];                          // 512 floats each
    sk[t >> 3][t & 7] = kp[t];
    ((float4*)sh)[t] = ((const float4*)hp)[t];          // 2048 floats
    if (t < R) {
        const float g = gamma_vec[t];
        float p = 1.f;
        for (int dl = 0; dl <= L; ++dl) { spow[t][dl] = p; p *= g; }
    }
    __syncthreads();

    // --- fused exclusive chunk-scan: threads 0..255 own one (r,d) scalar each.
    // Waves 0-3 do this while waves 4-7 proceed directly to the A-build below.
    if (t < 256) {
        const int r = t >> 5;
        float gL = gamma_vec[r];
#pragma unroll
        for (int s = 0; s < 6; ++s) gL *= gL;           // gamma^64
        float P = 0.f;
        const float* wsp = ws_state + (size_t)b * C * R * D + t;
        for (int cc = 0; cc < c; ++cc)                  // coalesced 1 KB loads, <=63 deep
            P = P * gL + wsp[(size_t)cc * R * D];
        s0[r][t & 31] = P;
    }

    // --- build A^T: lanes sweep i (conflict-free), j fixed per pass.
    for (int e = t; e < L * L; e += 512) {
        const int j = e >> 6, i = e & 63;
        float a = 0.f;
        if (j <= i) {
#pragma unroll
            for (int r = 0; r < R; ++r) a += sq[i][r] * sk[j][r] * spow[r][i - j];
        }
        sAT[j][i] = a;
    }
    __syncthreads();

    // --- outputs: thread -> (ig, d), i = ig*4 + s
    const int d = t & 31;
    const int ig = t >> 5;                              // 0..15
    float pr[R];
#pragma unroll
    for (int r = 0; r < R; ++r) pr[r] = s0[r][d];
    float acc[4];
#pragma unroll
    for (int s = 0; s < 4; ++s) {
        const int i = ig * 4 + s;
        float a = 0.f;
#pragma unroll
        for (int r = 0; r < R; ++r) a += sq[i][r] * spow[r][i + 1] * pr[r];
        acc[s] = a;
    }
    const int jmax = ig * 4 + 3;                        // triangular: A^T[j][i]=0 above diag
    for (int j = 0; j <= jmax; ++j) {
        const float hv = sh[j][d];                      // 1x b32, conflict-free
        const float4 av = *(const float4*)&sAT[j][ig * 4];  // 1x b128 broadcast (16B aligned)
        acc[0] += av.x * hv; acc[1] += av.y * hv;
        acc[2] += av.z * hv; acc[3] += av.w * hv;
    }
#pragma unroll
    for (int s = 0; s < 4; ++s)
        out[(row0 + (size_t)(ig * 4 + s)) * D + d] = acc[s];
}

extern "C" void kernel_launch(void* const* d_in, const int* in_sizes, int n_in,
                              void* d_out, int out_size, void* d_ws, size_t ws_size,
                              hipStream_t stream) {
    const float* q  = (const float*)d_in[0];   // [B,W,R]
    const float* k  = (const float*)d_in[1];   // [B,W,R]
    const float* h  = (const float*)d_in[2];   // [B,W,D]
    const float* gv = (const float*)d_in[3];   // [R]
    // d_in[4] (causal_mask) and d_in[5] (decay_diff) are implied analytically.
    float* out = (float*)d_out;                // [B,W,D] fp32
    float* ws  = (float*)d_ws;                 // B*C*R*D*4 = 128 KB used

    k_local<<<B * C, 512, 0, stream>>>(k, h, gv, ws);
    k_out  <<<B * C, 512, 0, stream>>>(q, k, h, gv, ws, out);
}

// Round 3
// 135.735 us; speedup vs baseline: 1.0907x; 1.0907x over previous
//
#include <hip/hip_runtime.h>

#define B 2
#define W 4096
#define R 8
#define D 32
#define L 64
#define C (W / L)   // 64 chunks

// gamma^e for e in [0,63] via repeated squaring: 6 mul+sel, no libm.
__device__ __forceinline__ float gpow6(float g, int e) {
    float p = 1.f;
    float b = g;
#pragma unroll
    for (int bit = 0; bit < 6; ++bit) {
        p = (e & (1 << bit)) ? p * b : p;
        b *= b;
    }
    return p;
}

// ---------------------------------------------------------------------------
// Kernel 1: per-chunk local decayed state
//   S_loc[b,c,r,d] = sum_{j=0..L-1} gamma_r^(L-1-j) * k[b,cL+j,r] * h[b,cL+j,d]
// 512 threads: even/odd-j split halves the serial decay chain (32 deep, g^2 step).
// ---------------------------------------------------------------------------
__global__ __launch_bounds__(512) void k_local(const float* __restrict__ kin,
                                               const float* __restrict__ hin,
                                               const float* __restrict__ gamma_vec,
                                               float* __restrict__ ws_state) {
    __shared__ float sk[L][R];        // 2 KB
    __shared__ float sh[L][D];        // 8 KB
    __shared__ float part[2][R][D];   // 2 KB
    const int blk = blockIdx.x;
    const int b = blk / C, c = blk % C;
    const int t = threadIdx.x;
    const float* kp = kin + ((size_t)b * W + (size_t)c * L) * R;   // [L][R]
    const float* hp = hin + ((size_t)b * W + (size_t)c * L) * D;   // [L][D]
    ((float*)sk)[t] = kp[t];                       // 512 floats
    ((float4*)sh)[t] = ((const float4*)hp)[t];     // 2048 floats
    __syncthreads();
    const int half = t >> 8;          // 0: even j, 1: odd j
    const int rd = t & 255;
    const int r = rd >> 5, d = rd & 31;
    const float g = gamma_vec[r];
    const float g2 = g * g;
    float S = 0.f;
#pragma unroll
    for (int m = 0; m < 32; ++m) {
        const int j = 2 * m + half;
        S = S * g2 + sk[j][r] * sh[j][d];
    }
    part[half][r][d] = S;
    __syncthreads();
    if (t < 256) {
        // g^(63-j): odd j -> (g^2)^((63-j)/2) = part[1]; even j -> g*(g^2)^((62-j)/2)
        ws_state[(size_t)(b * C + c) * R * D + rd] = part[1][r][d] + g * part[0][r][d];
    }
}

// ---------------------------------------------------------------------------
// Kernel 2 (fused scan + output), wave-specialized prologue:
//   waves 0-3: exclusive chunk-scan (8-way unrolled Horner, 8 loads in flight)
//   waves 4-7: stage h; stage q,k folded with decay:
//       qg[r][i] = q[i,r]*gamma_r^i,  kg[r][j] = k[j,r]*gamma_r^(-j)
//   then A^T[j][i] = sum_r qg[r][i]*kg[r][j]  (j<=i), out = qg.(g*P) + A.h
// ---------------------------------------------------------------------------
__global__ __launch_bounds__(512) void k_out(const float* __restrict__ qin,
                                             const float* __restrict__ kin,
                                             const float* __restrict__ hin,
                                             const float* __restrict__ gamma_vec,
                                             const float* __restrict__ ws_state,
                                             float* __restrict__ out) {
    __shared__ float sqg[R][L];                         // 2 KB, stride-1 in i: conflict-free
    __shared__ float skg[R][L];                         // 2 KB
    __shared__ float sh[L][D];                          // 8 KB
    __shared__ __align__(16) float sAT[L][L + 4];       // A^T [j][i], pad 68 (17 KB)
    __shared__ float s0[R][D];                          // gamma_r * P_c[r,d]
    const int blk = blockIdx.x;
    const int b = blk / C, c = blk % C;
    const int t = threadIdx.x;
    const size_t row0 = (size_t)b * W + (size_t)c * L;

    if (t >= 256) {
        // ---- staging half (waves 4-7) ----
        const int u = t - 256;
        const float* hp = hin + row0 * D;
        ((float4*)sh)[u]       = ((const float4*)hp)[u];        // 2048 floats total
        ((float4*)sh)[u + 256] = ((const float4*)hp)[u + 256];
        const int i = (u & 127) >> 1;       // each float4 covers (i, r0..r0+3)
        const int r0 = (u & 1) * 4;
        if (u < 128) {                      // waves 4-5: q -> qg = q * gamma^i
            const float4 v = ((const float4*)(qin + row0 * R))[u];
            sqg[r0 + 0][i] = v.x * gpow6(gamma_vec[r0 + 0], i);
            sqg[r0 + 1][i] = v.y * gpow6(gamma_vec[r0 + 1], i);
            sqg[r0 + 2][i] = v.z * gpow6(gamma_vec[r0 + 2], i);
            sqg[r0 + 3][i] = v.w * gpow6(gamma_vec[r0 + 3], i);
        } else {                            // waves 6-7: k -> kg = k * gamma^-j
            const float4 v = ((const float4*)(kin + row0 * R))[u - 128];
            skg[r0 + 0][i] = v.x * gpow6(1.f / gamma_vec[r0 + 0], i);
            skg[r0 + 1][i] = v.y * gpow6(1.f / gamma_vec[r0 + 1], i);
            skg[r0 + 2][i] = v.z * gpow6(1.f / gamma_vec[r0 + 2], i);
            skg[r0 + 3][i] = v.w * gpow6(1.f / gamma_vec[r0 + 3], i);
        }
    } else {
        // ---- scan half (waves 0-3): P = sum_{cc<c} (g^64)^(c-1-cc) * S_loc[cc] ----
        const int r = t >> 5;
        const float g = gamma_vec[r];
        float gL = g;
#pragma unroll
        for (int s = 0; s < 6; ++s) gL *= gL;           // gamma^64
        float gp[9];
        gp[0] = 1.f;
#pragma unroll
        for (int e = 1; e <= 8; ++e) gp[e] = gp[e - 1] * gL;
        float P = 0.f;
        const float* wsp = ws_state + (size_t)b * C * R * D + t;
        int cc = 0;
        const int head = c & 7;
        for (; cc < head; ++cc) P = P * gL + wsp[(size_t)cc * 256];
        for (; cc < c; cc += 8) {           // 8 independent loads in flight
            const float v0 = wsp[(size_t)(cc + 0) * 256];
            const float v1 = wsp[(size_t)(cc + 1) * 256];
            const float v2 = wsp[(size_t)(cc + 2) * 256];
            const float v3 = wsp[(size_t)(cc + 3) * 256];
            const float v4 = wsp[(size_t)(cc + 4) * 256];
            const float v5 = wsp[(size_t)(cc + 5) * 256];
            const float v6 = wsp[(size_t)(cc + 6) * 256];
            const float v7 = wsp[(size_t)(cc + 7) * 256];
            const float sg = v0 * gp[7] + v1 * gp[6] + v2 * gp[5] + v3 * gp[4]
                           + v4 * gp[3] + v5 * gp[2] + v6 * gp[1] + v7;
            P = P * gp[8] + sg;
        }
        s0[r][t & 31] = g * P;              // fold gamma^1: out uses qg * (g*P)
    }
    __syncthreads();

    // ---- A-build: i fixed per thread (hoisted qg), j wave-uniform per pass ----
    const int i = t & 63;
    const int w = t >> 6;                   // 0..7
    float qreg[R];
#pragma unroll
    for (int r = 0; r < R; ++r) qreg[r] = sqg[r][i];    // stride-1: conflict-free
#pragma unroll
    for (int p = 0; p < 8; ++p) {
        const int j = w + 8 * p;            // wave-uniform -> kg reads broadcast
        float a = 0.f;
#pragma unroll
        for (int r = 0; r < R; ++r) a += qreg[r] * skg[r][j];
        sAT[j][i] = (j <= i) ? a : 0.f;
    }
    __syncthreads();

    // ---- outputs: thread -> (ig, d), i = ig*4 + s ----
    const int d = t & 31;
    const int ig = t >> 5;                  // 0..15
    float pr[R];
#pragma unroll
    for (int r = 0; r < R; ++r) pr[r] = s0[r][d];
    float acc[4];
#pragma unroll
    for (int s = 0; s < 4; ++s) {
        const int i2 = ig * 4 + s;
        float a = 0.f;
#pragma unroll
        for (int r = 0; r < R; ++r) a += sqg[r][i2] * pr[r];   // broadcast reads
        acc[s] = a;
    }
    const int jmax = ig * 4 + 3;            // triangular: A^T[j][i]=0 above diag
    for (int j = 0; j <= jmax; ++j) {
        const float hv = sh[j][d];                          // conflict-free b32
        const float4 av = *(const float4*)&sAT[j][ig * 4];  // b128 broadcast, 16B aligned
        acc[0] += av.x * hv; acc[1] += av.y * hv;
        acc[2] += av.z * hv; acc[3] += av.w * hv;
    }
#pragma unroll
    for (int s = 0; s < 4; ++s)
        out[(row0 + (size_t)(ig * 4 + s)) * D + d] = acc[s];
}

extern "C" void kernel_launch(void* const* d_in, const int* in_sizes, int n_in,
                              void* d_out, int out_size, void* d_ws, size_t ws_size,
                              hipStream_t stream) {
    const float* q  = (const float*)d_in[0];   // [B,W,R]
    const float* k  = (const float*)d_in[1];   // [B,W,R]
    const float* h  = (const float*)d_in[2];   // [B,W,D]
    const float* gv = (const float*)d_in[3];   // [R]
    // d_in[4] (causal_mask) and d_in[5] (decay_diff) are implied analytically.
    float* out = (float*)d_out;                // [B,W,D] fp32
    float* ws  = (float*)d_ws;                 // B*C*R*D*4 = 128 KB used

    k_local<<<B * C, 512, 0, stream>>>(k, h, gv, ws);
    k_out  <<<B * C, 512, 0, stream>>>(q, k, h, gv, ws, out);
}